// Round 9
// baseline (174.173 us; speedup 1.0000x reference)
//
#include <hip/hip_runtime.h>

// GCN 2-layer, N=100k, E=3.2M, IN=2, HID=64, OUT=1 (all float32).
// R9: 98 buckets x 1024 nodes (CCH=5): halves partial traffic vs R8, cuts
// sort LDS-counter collisions; scans read packed edges as int4. Staged
// counting sort by dest bucket -> hist -> post1(dinv,y) -> s1 -> post2(MLP)
// -> s2 -> post3(out). Zero global atomics on hot paths (rare sort spills).

#define NBUCK 98
#define LBITS 10
#define BSH   1024
#define RBITS 17
#define RMASK ((1 << RBITS) - 1)
#define CAP   35000      // per-bucket packed region (mean 32.65k, +13 sigma)
#define SCAP  80         // per-block per-bucket staging (mean 64, +2 sigma)
#define SORTB 512
#define TPB   512
#define TPN   256
#define CCH   5          // chunks per bucket in scans (490 scan blocks)

__global__ void k_init0(int* __restrict__ gcur) {
    if (threadIdx.x < NBUCK) gcur[threadIdx.x] = threadIdx.x * CAP;
}

// staged counting sort by dest bucket: packed[b] gets ((lcol<<RBITS)|row)
__global__ void __launch_bounds__(TPB)
k_sort(const int* __restrict__ row, const int* __restrict__ col,
       int* __restrict__ gcur, int* __restrict__ packed, int E) {
    __shared__ int fill[NBUCK];
    __shared__ int gb[NBUCK];
    __shared__ int stage[NBUCK * SCAP];   // 31.4 KB
    const int tid = threadIdx.x, bid = blockIdx.x;
    if (tid < NBUCK) fill[tid] = 0;
    __syncthreads();
    const int q = E >> 2;
    const int q0 = (int)((long long)bid * q / SORTB);
    const int q1 = (int)((long long)(bid + 1) * q / SORTB);
    const int4* col4 = (const int4*)col;
    const int4* row4 = (const int4*)row;
    for (int i = q0 + tid; i < q1; i += TPB) {
        int4 c = col4[i], r = row4[i];
        int b, w, p;
        b = c.x >> LBITS; w = ((c.x & (BSH - 1)) << RBITS) | r.x;
        p = atomicAdd(&fill[b], 1);
        if (p < SCAP) stage[b * SCAP + p] = w; else packed[atomicAdd(&gcur[b], 1)] = w;
        b = c.y >> LBITS; w = ((c.y & (BSH - 1)) << RBITS) | r.y;
        p = atomicAdd(&fill[b], 1);
        if (p < SCAP) stage[b * SCAP + p] = w; else packed[atomicAdd(&gcur[b], 1)] = w;
        b = c.z >> LBITS; w = ((c.z & (BSH - 1)) << RBITS) | r.z;
        p = atomicAdd(&fill[b], 1);
        if (p < SCAP) stage[b * SCAP + p] = w; else packed[atomicAdd(&gcur[b], 1)] = w;
        b = c.w >> LBITS; w = ((c.w & (BSH - 1)) << RBITS) | r.w;
        p = atomicAdd(&fill[b], 1);
        if (p < SCAP) stage[b * SCAP + p] = w; else packed[atomicAdd(&gcur[b], 1)] = w;
    }
    if (bid == SORTB - 1) {   // scalar tail if E%4 != 0
        for (int e = (q << 2) + tid; e < E; e += TPB) {
            int c = col[e];
            int b = c >> LBITS, w = ((c & (BSH - 1)) << RBITS) | row[e];
            int p = atomicAdd(&fill[b], 1);
            if (p < SCAP) stage[b * SCAP + p] = w; else packed[atomicAdd(&gcur[b], 1)] = w;
        }
    }
    __syncthreads();
    if (tid < NBUCK) {
        int cnt = min(fill[tid], SCAP);
        gb[tid] = atomicAdd(&gcur[tid], cnt);
    }
    __syncthreads();
    const int wid = tid >> 6, lane = tid & 63;
    for (int b = wid; b < NBUCK; b += (TPB >> 6)) {   // per-wave coalesced copy-out
        int cnt = min(fill[b], SCAP);
        int gp = gb[b];
        for (int i = lane; i < cnt; i += 64)
            packed[gp + i] = stage[b * SCAP + i];
    }
}

// in-degree histogram from bucket-sorted packed edges (4KB LDS, int4 reads)
__global__ void __launch_bounds__(TPB)
k_hist(const int* __restrict__ gcur, const int* __restrict__ packed,
       int* __restrict__ pbi) {
    __shared__ int s[BSH];
    const int b = blockIdx.x / CCH, j = blockIdx.x - b * CCH;
    for (int i = threadIdx.x; i < BSH; i += TPB) s[i] = 0;
    __syncthreads();
    const int base = b * CAP;
    const int len = gcur[b] - base;
    const int q = len >> 2;
    const int q0 = (int)((long long)q * j / CCH);
    const int q1 = (int)((long long)q * (j + 1) / CCH);
    const int4* p4 = (const int4*)(packed + base);
    for (int i = q0 + threadIdx.x; i < q1; i += TPB) {
        int4 w = p4[i];
        atomicAdd(&s[w.x >> RBITS], 1);
        atomicAdd(&s[w.y >> RBITS], 1);
        atomicAdd(&s[w.z >> RBITS], 1);
        atomicAdd(&s[w.w >> RBITS], 1);
    }
    if (j == CCH - 1)
        for (int e = (q << 2) + threadIdx.x; e < len; e += TPB)
            atomicAdd(&s[packed[base + e] >> RBITS], 1);
    __syncthreads();
    int4* dst = (int4*)(pbi + ((size_t)blockIdx.x << LBITS));
    const int4* src = (const int4*)s;
    for (int i = threadIdx.x; i < (BSH >> 2); i += TPB) dst[i] = src[i];
}

// merge hist partials -> dinv; y = dinv*x
__global__ void __launch_bounds__(TPN)
k_post1(const int* __restrict__ pbi, const float2* __restrict__ x,
        float* __restrict__ dinv, float2* __restrict__ y, int n) {
    int i = blockIdx.x * TPN + threadIdx.x;
    if (i >= n) return;
    const int b = i >> LBITS, l = i & (BSH - 1);
    int deg = 1;  // self-loop
    const int* p = pbi + ((size_t)(b * CCH) << LBITS) + l;
#pragma unroll
    for (int j = 0; j < CCH; ++j) deg += p[j << LBITS];
    float d = rsqrtf((float)deg);
    dinv[i] = d;
    float2 xv = x[i];
    y[i] = make_float2(d * xv.x, d * xv.y);
}

// layer-1 scatter: s[lcol] += y[row] (8KB LDS, int4 reads)
__global__ void __launch_bounds__(TPB)
k_s1(const int* __restrict__ gcur, const int* __restrict__ packed,
     const float2* __restrict__ y, float2* __restrict__ pbf2) {
    __shared__ float2 s[BSH];
    const int b = blockIdx.x / CCH, j = blockIdx.x - b * CCH;
    for (int i = threadIdx.x; i < BSH; i += TPB) s[i] = make_float2(0.f, 0.f);
    __syncthreads();
    const int base = b * CAP;
    const int len = gcur[b] - base;
    const int q = len >> 2;
    const int q0 = (int)((long long)q * j / CCH);
    const int q1 = (int)((long long)q * (j + 1) / CCH);
    const int4* p4 = (const int4*)(packed + base);
    for (int i = q0 + threadIdx.x; i < q1; i += TPB) {
        int4 w = p4[i];
        float2 v; float* sp;
        v = y[w.x & RMASK]; sp = (float*)&s[w.x >> RBITS];
        atomicAdd(sp, v.x); atomicAdd(sp + 1, v.y);
        v = y[w.y & RMASK]; sp = (float*)&s[w.y >> RBITS];
        atomicAdd(sp, v.x); atomicAdd(sp + 1, v.y);
        v = y[w.z & RMASK]; sp = (float*)&s[w.z >> RBITS];
        atomicAdd(sp, v.x); atomicAdd(sp + 1, v.y);
        v = y[w.w & RMASK]; sp = (float*)&s[w.w >> RBITS];
        atomicAdd(sp, v.x); atomicAdd(sp + 1, v.y);
    }
    if (j == CCH - 1)
        for (int e = (q << 2) + threadIdx.x; e < len; e += TPB) {
            int w = packed[base + e];
            float2 v = y[w & RMASK];
            float* sp = (float*)&s[w >> RBITS];
            atomicAdd(sp, v.x); atomicAdd(sp + 1, v.y);
        }
    __syncthreads();
    float4* dst = (float4*)(pbf2 + ((size_t)blockIdx.x << LBITS));
    const float4* src = (const float4*)s;
    for (int i = threadIdx.x; i < (BSH >> 1); i += TPB) dst[i] = src[i];
}

// merge layer-1 partials + per-node MLP: t = dinv*(relu(a@W1+b1)@W2)
__global__ void __launch_bounds__(TPN)
k_post2(const float2* __restrict__ pbf2, const float* __restrict__ dinv,
        const float2* __restrict__ y,
        const float* __restrict__ W1, const float* __restrict__ B1,
        const float* __restrict__ W2, float* __restrict__ t, int n) {
    __shared__ float w1a[64], w1b[64], bb1[64], w2[64];
    if (threadIdx.x < 64) {
        w1a[threadIdx.x] = W1[threadIdx.x];
        w1b[threadIdx.x] = W1[64 + threadIdx.x];
        bb1[threadIdx.x] = B1[threadIdx.x];
        w2[threadIdx.x]  = W2[threadIdx.x];
    }
    __syncthreads();
    int i = blockIdx.x * TPN + threadIdx.x;
    if (i >= n) return;
    const int b = i >> LBITS, l = i & (BSH - 1);
    float gx = 0.f, gy = 0.f;
    const float2* p = pbf2 + ((size_t)(b * CCH) << LBITS) + l;
#pragma unroll
    for (int j = 0; j < CCH; ++j) { float2 v = p[j << LBITS]; gx += v.x; gy += v.y; }
    float d = dinv[i];
    float2 yv = y[i];
    float a0 = d * (gx + yv.x);
    float a1 = d * (gy + yv.y);
    float acc = 0.f;
#pragma unroll
    for (int h = 0; h < 64; ++h) {
        float v = fmaf(a0, w1a[h], fmaf(a1, w1b[h], bb1[h]));
        acc = fmaf(fmaxf(v, 0.f), w2[h], acc);
    }
    t[i] = d * acc;
}

// layer-2 scatter: s[lcol] += t[row] (4KB LDS, int4 reads)
__global__ void __launch_bounds__(TPB)
k_s2(const int* __restrict__ gcur, const int* __restrict__ packed,
     const float* __restrict__ t, float* __restrict__ pbf) {
    __shared__ float s[BSH];
    const int b = blockIdx.x / CCH, j = blockIdx.x - b * CCH;
    for (int i = threadIdx.x; i < BSH; i += TPB) s[i] = 0.f;
    __syncthreads();
    const int base = b * CAP;
    const int len = gcur[b] - base;
    const int q = len >> 2;
    const int q0 = (int)((long long)q * j / CCH);
    const int q1 = (int)((long long)q * (j + 1) / CCH);
    const int4* p4 = (const int4*)(packed + base);
    for (int i = q0 + threadIdx.x; i < q1; i += TPB) {
        int4 w = p4[i];
        atomicAdd(&s[w.x >> RBITS], t[w.x & RMASK]);
        atomicAdd(&s[w.y >> RBITS], t[w.y & RMASK]);
        atomicAdd(&s[w.z >> RBITS], t[w.z & RMASK]);
        atomicAdd(&s[w.w >> RBITS], t[w.w & RMASK]);
    }
    if (j == CCH - 1)
        for (int e = (q << 2) + threadIdx.x; e < len; e += TPB) {
            int w = packed[base + e];
            atomicAdd(&s[w >> RBITS], t[w & RMASK]);
        }
    __syncthreads();
    float4* dst = (float4*)(pbf + ((size_t)blockIdx.x << LBITS));
    const float4* src = (const float4*)s;
    for (int i = threadIdx.x; i < (BSH >> 2); i += TPB) dst[i] = src[i];
}

// merge layer-2 partials + epilogue
__global__ void __launch_bounds__(TPN)
k_post3(const float* __restrict__ pbf, const float* __restrict__ t,
        const float* __restrict__ dinv, const float* __restrict__ B2,
        float* __restrict__ out, int n) {
    int i = blockIdx.x * TPN + threadIdx.x;
    if (i >= n) return;
    const int b = i >> LBITS, l = i & (BSH - 1);
    float o = 0.f;
    const float* p = pbf + ((size_t)(b * CCH) << LBITS) + l;
#pragma unroll
    for (int j = 0; j < CCH; ++j) o += p[j << LBITS];
    out[i] = fmaf(dinv[i], o + t[i], B2[0]);
}

extern "C" void kernel_launch(void* const* d_in, const int* in_sizes, int n_in,
                              void* d_out, int out_size, void* d_ws, size_t ws_size,
                              hipStream_t stream) {
    const float* x  = (const float*)d_in[0];
    const int*   ei = (const int*)d_in[1];
    const float* W1 = (const float*)d_in[2];
    const float* B1 = (const float*)d_in[3];
    const float* W2 = (const float*)d_in[4];
    const float* B2 = (const float*)d_in[5];
    float* out = (float*)d_out;

    const int n = in_sizes[0] / 2;      // 100,000
    const int E = in_sizes[1] / 2;      // 3,200,000
    const int* row = ei;
    const int* col = ei + E;

    // ws: dinv[n] | y[n](f2) | t[n] | gcur | packed[98*CAP ~13.7MB] | pb (4MB)
    char* ws = (char*)d_ws;
    size_t off = 0;
    float*  dinv = (float*)(ws + off);  off += (size_t)n * 4;
    float2* y    = (float2*)(ws + off); off += (size_t)n * 8;
    float*  t    = (float*)(ws + off);  off += (size_t)n * 4;
    off = (off + 255) & ~(size_t)255;
    int* gcur    = (int*)(ws + off);    off += 512;
    int* packed  = (int*)(ws + off);    off += (size_t)NBUCK * CAP * 4;
    off = (off + 255) & ~(size_t)255;
    float* pb    = (float*)(ws + off);

    const int gnode = (n + TPN - 1) / TPN;
    const int gscan = NBUCK * CCH;

    k_init0<<<1, 128, 0, stream>>>(gcur);
    k_sort <<<SORTB, TPB, 0, stream>>>(row, col, gcur, packed, E);
    k_hist <<<gscan, TPB, 0, stream>>>(gcur, packed, (int*)pb);
    k_post1<<<gnode, TPN, 0, stream>>>((const int*)pb, (const float2*)x, dinv, y, n);
    k_s1   <<<gscan, TPB, 0, stream>>>(gcur, packed, y, (float2*)pb);
    k_post2<<<gnode, TPN, 0, stream>>>((const float2*)pb, dinv, y, W1, B1, W2, t, n);
    k_s2   <<<gscan, TPB, 0, stream>>>(gcur, packed, t, pb);
    k_post3<<<gnode, TPN, 0, stream>>>(pb, t, dinv, B2, out, n);
}

// Round 10
// 166.607 us; speedup vs baseline: 1.0454x; 1.0454x over previous
//
#include <hip/hip_runtime.h>

// GCN 2-layer, N=100k, E=3.2M, IN=2, HID=64, OUT=1 (all float32).
// R10: CCH=1 full-fusion. 256 buckets x 392 nodes (magic-div, 1 block/CU in
// scans). Each scan block owns a whole bucket in LDS and applies the per-node
// epilogue inline: hist->dinv,y | s1->MLP->t | s2->out. No partial buffers,
// no merge kernels: 5 launches total. Staged counting sort (1024 blocks,
// SCAP=28, ~30KB LDS -> 2 blocks/CU) groups edges by dest bucket; scans read
// each edge exactly once as int4.

#define NBUCK 256
#define BSH   392        // nodes per bucket (256*392 = 100352 >= n)
#define RBITS 17         // row bits (n < 131072)
#define RMASK ((1 << RBITS) - 1)
#define CAP   13500      // packed region per bucket (mean 12.5k, +9 sigma)
#define SORTB 1024
#define SCAPS 28         // staging per (block,bucket): mean 12.2, ~+4.5 sigma
#define TPS   512
#define TPB   1024

__global__ void k_init0(int* __restrict__ gcur) {
    if (threadIdx.x < NBUCK) gcur[threadIdx.x] = threadIdx.x * CAP;
}

__device__ __forceinline__ void sort_one(int c, int r, int* fill, int* stage,
                                         int* __restrict__ gcur,
                                         int* __restrict__ packed) {
    int b = (int)((unsigned)c / (unsigned)BSH);   // magic-mul div by 392
    int l = c - b * BSH;
    int w = (l << RBITS) | r;
    int p = atomicAdd(&fill[b], 1);
    if (p < SCAPS) stage[b * SCAPS + p] = w;
    else packed[atomicAdd(&gcur[b], 1)] = w;      // rare spill, still correct
}

// staged counting sort by dest bucket: packed[b-region] gets ((lcol<<17)|row)
__global__ void __launch_bounds__(TPS)
k_sort(const int* __restrict__ row, const int* __restrict__ col,
       int* __restrict__ gcur, int* __restrict__ packed, int E) {
    __shared__ int fill[NBUCK];
    __shared__ int gb[NBUCK];
    __shared__ int stage[NBUCK * SCAPS];   // 28,672 B
    const int tid = threadIdx.x, bid = blockIdx.x;
    for (int i = tid; i < NBUCK; i += TPS) fill[i] = 0;
    __syncthreads();
    const int q = E >> 2;
    const int q0 = (int)((long long)bid * q / SORTB);
    const int q1 = (int)((long long)(bid + 1) * q / SORTB);
    const int4* c4 = (const int4*)col;
    const int4* r4 = (const int4*)row;
    for (int i = q0 + tid; i < q1; i += TPS) {
        int4 c = c4[i], r = r4[i];
        sort_one(c.x, r.x, fill, stage, gcur, packed);
        sort_one(c.y, r.y, fill, stage, gcur, packed);
        sort_one(c.z, r.z, fill, stage, gcur, packed);
        sort_one(c.w, r.w, fill, stage, gcur, packed);
    }
    if (bid == SORTB - 1)   // tail if E % 4 != 0
        for (int e = (q << 2) + tid; e < E; e += TPS)
            sort_one(col[e], row[e], fill, stage, gcur, packed);
    __syncthreads();
    for (int b = tid; b < NBUCK; b += TPS)
        gb[b] = atomicAdd(&gcur[b], min(fill[b], SCAPS));
    __syncthreads();
    const int wid = tid >> 6, lane = tid & 63;
    for (int b = wid; b < NBUCK; b += (TPS >> 6)) {   // per-wave coalesced copy-out
        int cnt = min(fill[b], SCAPS);
        int gp = gb[b];
        for (int i = lane; i < cnt; i += 64)
            packed[gp + i] = stage[b * SCAPS + i];
    }
}

// hist + epilogue: deg -> dinv; y = dinv*x   (one block = one whole bucket)
__global__ void __launch_bounds__(TPB)
k_h1(const int* __restrict__ gcur, const int* __restrict__ packed,
     const float2* __restrict__ x, float* __restrict__ dinv,
     float2* __restrict__ y, int n) {
    __shared__ int s[BSH];
    const int b = blockIdx.x;
    for (int i = threadIdx.x; i < BSH; i += TPB) s[i] = 0;
    __syncthreads();
    const int base = b * CAP;
    const int len = gcur[b] - base;
    const int q = len >> 2;
    const int4* p4 = (const int4*)(packed + base);
    for (int i = threadIdx.x; i < q; i += TPB) {
        int4 w = p4[i];
        atomicAdd(&s[w.x >> RBITS], 1);
        atomicAdd(&s[w.y >> RBITS], 1);
        atomicAdd(&s[w.z >> RBITS], 1);
        atomicAdd(&s[w.w >> RBITS], 1);
    }
    for (int e = (q << 2) + threadIdx.x; e < len; e += TPB)
        atomicAdd(&s[packed[base + e] >> RBITS], 1);
    __syncthreads();
    for (int l = threadIdx.x; l < BSH; l += TPB) {
        int i = b * BSH + l;
        if (i < n) {
            float d = rsqrtf((float)(1 + s[l]));   // +1 self-loop
            dinv[i] = d;
            float2 xv = x[i];
            y[i] = make_float2(d * xv.x, d * xv.y);
        }
    }
}

// s1 + MLP epilogue: agg = sum y[row]; t = dinv*(relu((dinv*(agg+y))@W1+b1)@W2)
__global__ void __launch_bounds__(TPB)
k_sc1(const int* __restrict__ gcur, const int* __restrict__ packed,
      const float2* __restrict__ y, const float* __restrict__ dinv,
      const float* __restrict__ W1, const float* __restrict__ B1,
      const float* __restrict__ W2, float* __restrict__ t, int n) {
    __shared__ float2 s[BSH];
    __shared__ float w1a[64], w1b[64], bb1[64], w2[64];
    if (threadIdx.x < 64) {
        w1a[threadIdx.x] = W1[threadIdx.x];
        w1b[threadIdx.x] = W1[64 + threadIdx.x];
        bb1[threadIdx.x] = B1[threadIdx.x];
        w2[threadIdx.x]  = W2[threadIdx.x];
    }
    for (int i = threadIdx.x; i < BSH; i += TPB) s[i] = make_float2(0.f, 0.f);
    __syncthreads();
    const int b = blockIdx.x;
    const int base = b * CAP;
    const int len = gcur[b] - base;
    const int q = len >> 2;
    const int4* p4 = (const int4*)(packed + base);
    for (int i = threadIdx.x; i < q; i += TPB) {
        int4 w = p4[i];
        float2 v; float* sp;
        v = y[w.x & RMASK]; sp = (float*)&s[w.x >> RBITS];
        atomicAdd(sp, v.x); atomicAdd(sp + 1, v.y);
        v = y[w.y & RMASK]; sp = (float*)&s[w.y >> RBITS];
        atomicAdd(sp, v.x); atomicAdd(sp + 1, v.y);
        v = y[w.z & RMASK]; sp = (float*)&s[w.z >> RBITS];
        atomicAdd(sp, v.x); atomicAdd(sp + 1, v.y);
        v = y[w.w & RMASK]; sp = (float*)&s[w.w >> RBITS];
        atomicAdd(sp, v.x); atomicAdd(sp + 1, v.y);
    }
    for (int e = (q << 2) + threadIdx.x; e < len; e += TPB) {
        int w = packed[base + e];
        float2 v = y[w & RMASK];
        float* sp = (float*)&s[w >> RBITS];
        atomicAdd(sp, v.x); atomicAdd(sp + 1, v.y);
    }
    __syncthreads();
    for (int l = threadIdx.x; l < BSH; l += TPB) {
        int i = b * BSH + l;
        if (i < n) {
            float d = dinv[i];
            float2 yv = y[i];
            float a0 = d * (s[l].x + yv.x);
            float a1 = d * (s[l].y + yv.y);
            float acc = 0.f;
#pragma unroll
            for (int h = 0; h < 64; ++h) {
                float v = fmaf(a0, w1a[h], fmaf(a1, w1b[h], bb1[h]));
                acc = fmaf(fmaxf(v, 0.f), w2[h], acc);
            }
            t[i] = d * acc;
        }
    }
}

// s2 + output epilogue: o = sum t[row]; out = dinv*(o + t_self) + b2
__global__ void __launch_bounds__(TPB)
k_sc2(const int* __restrict__ gcur, const int* __restrict__ packed,
      const float* __restrict__ t, const float* __restrict__ dinv,
      const float* __restrict__ B2, float* __restrict__ out, int n) {
    __shared__ float s[BSH];
    const int b = blockIdx.x;
    for (int i = threadIdx.x; i < BSH; i += TPB) s[i] = 0.f;
    __syncthreads();
    const int base = b * CAP;
    const int len = gcur[b] - base;
    const int q = len >> 2;
    const int4* p4 = (const int4*)(packed + base);
    for (int i = threadIdx.x; i < q; i += TPB) {
        int4 w = p4[i];
        atomicAdd(&s[w.x >> RBITS], t[w.x & RMASK]);
        atomicAdd(&s[w.y >> RBITS], t[w.y & RMASK]);
        atomicAdd(&s[w.z >> RBITS], t[w.z & RMASK]);
        atomicAdd(&s[w.w >> RBITS], t[w.w & RMASK]);
    }
    for (int e = (q << 2) + threadIdx.x; e < len; e += TPB) {
        int w = packed[base + e];
        atomicAdd(&s[w >> RBITS], t[w & RMASK]);
    }
    __syncthreads();
    for (int l = threadIdx.x; l < BSH; l += TPB) {
        int i = b * BSH + l;
        if (i < n) out[i] = fmaf(dinv[i], s[l] + t[i], B2[0]);
    }
}

extern "C" void kernel_launch(void* const* d_in, const int* in_sizes, int n_in,
                              void* d_out, int out_size, void* d_ws, size_t ws_size,
                              hipStream_t stream) {
    const float* x  = (const float*)d_in[0];
    const int*   ei = (const int*)d_in[1];
    const float* W1 = (const float*)d_in[2];
    const float* B1 = (const float*)d_in[3];
    const float* W2 = (const float*)d_in[4];
    const float* B2 = (const float*)d_in[5];
    float* out = (float*)d_out;

    const int n = in_sizes[0] / 2;      // 100,000
    const int E = in_sizes[1] / 2;      // 3,200,000
    const int* row = ei;
    const int* col = ei + E;

    // ws: dinv[n] | y[n](f2) | t[n] | gcur[256] | packed[256*CAP ~13.8MB]
    char* ws = (char*)d_ws;
    size_t off = 0;
    float*  dinv = (float*)(ws + off);  off += (size_t)n * 4;
    float2* y    = (float2*)(ws + off); off += (size_t)n * 8;
    float*  t    = (float*)(ws + off);  off += (size_t)n * 4;
    off = (off + 255) & ~(size_t)255;
    int* gcur    = (int*)(ws + off);    off += (size_t)NBUCK * 4;
    off = (off + 255) & ~(size_t)255;
    int* packed  = (int*)(ws + off);

    k_init0<<<1, NBUCK, 0, stream>>>(gcur);
    k_sort <<<SORTB, TPS, 0, stream>>>(row, col, gcur, packed, E);
    k_h1   <<<NBUCK, TPB, 0, stream>>>(gcur, packed, (const float2*)x, dinv, y, n);
    k_sc1  <<<NBUCK, TPB, 0, stream>>>(gcur, packed, y, dinv, W1, B1, W2, t, n);
    k_sc2  <<<NBUCK, TPB, 0, stream>>>(gcur, packed, t, dinv, B2, out, n);
}